// Round 2
// baseline (301.381 us; speedup 1.0000x reference)
//
#include <hip/hip_runtime.h>

typedef __attribute__((ext_vector_type(8))) short bf16x8;
typedef __attribute__((ext_vector_type(4))) float f32x4;
typedef unsigned short u16;

#define MFMA16(a,b,c) __builtin_amdgcn_mfma_f32_16x16x32_bf16((a),(b),(c),0,0,0)

__device__ __forceinline__ u16 f2bf(float f){
  unsigned int u = __float_as_uint(f);
  u += 0x7fffu + ((u >> 16) & 1u);
  return (u16)(u >> 16);
}

__device__ __forceinline__ void gload16(const void* g, void* l){
  __builtin_amdgcn_global_load_lds(
      (__attribute__((address_space(1))) void*)g,
      (__attribute__((address_space(3))) void*)l, 16, 0, 0);
}

// ---------------- prepass: fp32 -> bf16 flat convert ----------------
__global__ __launch_bounds__(256) void mqa_cvt(const float* __restrict__ in,
                                               u16* __restrict__ out, int n8){
  int i = blockIdx.x * 256 + threadIdx.x;
  if (i >= n8) return;
  const float4* p = (const float4*)in;
  float4 a = p[2*i], b = p[2*i+1];
  u16 o[8] = { f2bf(a.x), f2bf(a.y), f2bf(a.z), f2bf(a.w),
               f2bf(b.x), f2bf(b.y), f2bf(b.z), f2bf(b.w) };
  *(bf16x8*)&out[(size_t)i*8] = *(bf16x8*)o;
}

// ---------------- prepass: transpose-convert  in[R][C] f32 -> out[C][R] bf16
__global__ __launch_bounds__(256) void mqa_tcvt(const float* __restrict__ in,
                                                u16* __restrict__ out, int R, int C){
  __shared__ float t[32][33];
  int c0 = blockIdx.x * 32, r0 = blockIdx.y * 32;
  int x = threadIdx.x & 31, y0 = threadIdx.x >> 5;
  #pragma unroll
  for (int yy = y0; yy < 32; yy += 8)
    t[yy][x] = in[(size_t)(r0 + yy) * C + c0 + x];
  __syncthreads();
  #pragma unroll
  for (int yy = y0; yy < 32; yy += 8)
    out[(size_t)(c0 + yy) * R + r0 + x] = f2bf(t[x][yy]);
}

// ---------------- GEMM: A[M][K] bf16 row-major, Bt[N][K] bf16 row-major ----
// C = A * Bt^T.  EPI 0: write fp32 to outF[M][N].  EPI 1: QKV scatter
// (V is stored k-PERMUTED: within each 128-k block, pos = (k&15)*8 + (k>>4),
//  matching the attention P-LDS layout so PV fragments stay contiguous).
template<int EPI>
__global__ __launch_bounds__(256, 2) void mqa_gemm(
    const u16* __restrict__ A, const u16* __restrict__ Bt,
    float* __restrict__ outF, u16* __restrict__ Qb, u16* __restrict__ Kb,
    u16* __restrict__ Vtb, int M, int N, int K, int NT)
{
  __shared__ __align__(16) u16 lds_a[128*32];
  __shared__ __align__(16) u16 lds_b[128*32];
  int bx = blockIdx.x;
  int mt = bx / NT, nt = bx % NT;
  int m0 = mt * 128, n0 = nt * 128;
  int tid = threadIdx.x;
  int wid = tid >> 6, lane = tid & 63;
  int wrow = (wid >> 1) * 64, wcol = (wid & 1) * 64;
  int lrow = lane >> 2;          // staging: row within 16-row chunk
  int lk   = (lane & 3) * 8;     // staging: k offset (8 bf16 = 16B)
  int fr = lane & 15, g8 = (lane >> 4) * 8, fg = lane >> 4;

  f32x4 acc[4][4];
  #pragma unroll
  for (int i = 0; i < 4; ++i)
    #pragma unroll
    for (int j = 0; j < 4; ++j) acc[i][j] = (f32x4)0.f;

  for (int k0 = 0; k0 < K; k0 += 32) {
    #pragma unroll
    for (int c = wid; c < 8; c += 4) {
      gload16(&A [(size_t)(m0 + c*16 + lrow) * K + k0 + lk], &lds_a[c*512]);
      gload16(&Bt[(size_t)(n0 + c*16 + lrow) * K + k0 + lk], &lds_b[c*512]);
    }
    __syncthreads();
    bf16x8 af[4], bfr[4];
    #pragma unroll
    for (int i = 0; i < 4; ++i) af[i] = *(const bf16x8*)&lds_a[(wrow + i*16 + fr)*32 + g8];
    #pragma unroll
    for (int j = 0; j < 4; ++j) bfr[j] = *(const bf16x8*)&lds_b[(wcol + j*16 + fr)*32 + g8];
    #pragma unroll
    for (int i = 0; i < 4; ++i)
      #pragma unroll
      for (int j = 0; j < 4; ++j)
        acc[i][j] = MFMA16(af[i], bfr[j], acc[i][j]);
    __syncthreads();
  }

  #pragma unroll
  for (int i = 0; i < 4; ++i) {
    #pragma unroll
    for (int j = 0; j < 4; ++j) {
      int ncol = n0 + wcol + j*16 + fr;
      #pragma unroll
      for (int r = 0; r < 4; ++r) {
        int m = m0 + wrow + i*16 + fg*4 + r;
        float v = acc[i][j][r];
        if (EPI == 0) {
          outF[(size_t)m * N + ncol] = v;
        } else {
          u16 bv = f2bf(v);
          if (ncol < 1024) {
            Qb[(size_t)m * 1024 + ncol] = bv;              // Q [B,S,H*HD]
          } else if (ncol < 1088) {
            Kb[(size_t)m * 64 + (ncol - 1024)] = bv;       // K [B,S,HD]
          } else {
            int b = m >> 11, s = m & 2047;                 // Vp [B,HD,S-permuted]
            int p = ((s & 15) << 3) | ((s >> 4) & 7);
            Vtb[((size_t)b * 64 + (ncol - 1088)) * 2048 + (s & ~127) + p] = bv;
          }
        }
      }
    }
  }
}

// ---------------- flash MQA attention ----------------
// grid (S/64, H, B), 256 threads = 4 waves; wave w owns q rows [qt*64+w*16,+16)
__global__ __launch_bounds__(256, 4) void mqa_attn(
    const u16* __restrict__ Qb, const u16* __restrict__ Kb,
    const u16* __restrict__ Vtb, u16* __restrict__ Ctx)
{
  const float C1 = 0.18033688011112042f;  // (1/8) * log2(e)
  int qt = blockIdx.x, h = blockIdx.y, b = blockIdx.z;
  int tid = threadIdx.x, wid = tid >> 6, lane = tid & 63;
  int fr = lane & 15, g = lane >> 4;
  int q0 = qt * 64 + wid * 16;

  // per-wave private P tile: 16 rows x 136 (pad) u16; k-axis stored PERMUTED:
  // column (k&15)*8 + (k>>4)  -> lane-local exp pairs are LDS-adjacent (b32 writes)
  __shared__ __align__(16) u16 P_lds[4][16 * 136];
  u16* Pw = &P_lds[wid][0];

  const u16* Qbase = Qb + (size_t)b * 2048 * 1024 + (size_t)h * 64;
  const u16* Kbase = Kb + (size_t)b * 2048 * 64;
  const u16* Vbase = Vtb + (size_t)b * 64 * 2048;

  bf16x8 qf[2];
  #pragma unroll
  for (int ks = 0; ks < 2; ++ks)
    qf[ks] = *(const bf16x8*)&Qbase[(size_t)(q0 + fr) * 1024 + ks*32 + g*8];

  f32x4 oacc[4];
  float mrow[4], lrw[4];
  #pragma unroll
  for (int vf = 0; vf < 4; ++vf) oacc[vf] = (f32x4)0.f;
  #pragma unroll
  for (int r = 0; r < 4; ++r) { mrow[r] = -1e30f; lrw[r] = 0.f; }

  for (int kb = 0; kb < 16; ++kb) {
    const int sk0 = kb * 128;
    f32x4 sacc[8];
    #pragma unroll
    for (int cf = 0; cf < 8; ++cf) sacc[cf] = (f32x4)0.f;

    // S = Q K^T (raw; scale folded into exp2 constant)
    __builtin_amdgcn_s_setprio(1);
    #pragma unroll
    for (int ks = 0; ks < 2; ++ks) {
      #pragma unroll
      for (int cf = 0; cf < 8; ++cf) {
        bf16x8 kf = *(const bf16x8*)&Kbase[(size_t)(sk0 + cf*16 + fr) * 64 + ks*32 + g*8];
        sacc[cf] = MFMA16(qf[ks], kf, sacc[cf]);
      }
    }
    __builtin_amdgcn_s_setprio(0);

    // online softmax: row q = g*4+r lives across the 16 fr-lanes
    float corr[4], rs[4], mC1[4];
    #pragma unroll
    for (int r = 0; r < 4; ++r) {
      float mx = sacc[0][r];
      #pragma unroll
      for (int cf = 1; cf < 8; ++cf) mx = fmaxf(mx, sacc[cf][r]);
      #pragma unroll
      for (int off = 1; off < 16; off <<= 1) mx = fmaxf(mx, __shfl_xor(mx, off));
      float mn = fmaxf(mrow[r], mx);
      corr[r] = __builtin_amdgcn_exp2f((mrow[r] - mn) * C1);
      mrow[r] = mn;
      lrw[r] *= corr[r];
      rs[r] = 0.f;
      mC1[r] = mn * C1;
    }
    #pragma unroll
    for (int vf = 0; vf < 4; ++vf)
      #pragma unroll
      for (int r = 0; r < 4; ++r) oacc[vf][r] *= corr[r];

    // exp -> packed bf16 pair -> one ds_write_b32 (16 writes/lane)
    #pragma unroll
    for (int t = 0; t < 4; ++t) {
      #pragma unroll
      for (int r = 0; r < 4; ++r) {
        float p0 = __builtin_amdgcn_exp2f(sacc[2*t  ][r] * C1 - mC1[r]);
        float p1 = __builtin_amdgcn_exp2f(sacc[2*t+1][r] * C1 - mC1[r]);
        rs[r] += p0 + p1;
        unsigned int pk;
        asm("v_cvt_pk_bf16_f32 %0, %1, %2" : "=v"(pk) : "v"(p0), "v"(p1));
        *(unsigned int*)&Pw[(g*4 + r) * 136 + fr*8 + 2*t] = pk;
      }
    }
    #pragma unroll
    for (int r = 0; r < 4; ++r) {
      float tsum = rs[r];
      #pragma unroll
      for (int off = 1; off < 16; off <<= 1) tsum += __shfl_xor(tsum, off);
      lrw[r] += tsum;
    }

    // ctx += P V  (P A-frags from LDS; V^T permuted frags straight from L2)
    __builtin_amdgcn_s_setprio(1);
    #pragma unroll
    for (int ks2 = 0; ks2 < 4; ++ks2) {
      bf16x8 pf = *(const bf16x8*)&Pw[fr * 136 + ks2*32 + g*8];
      #pragma unroll
      for (int vf = 0; vf < 4; ++vf) {
        bf16x8 vfr = *(const bf16x8*)&Vbase[(size_t)(vf*16 + fr) * 2048 + sk0 + ks2*32 + g*8];
        oacc[vf] = MFMA16(pf, vfr, oacc[vf]);
      }
    }
    __builtin_amdgcn_s_setprio(0);
  }

  // write ctx [B,S,H*HD] bf16
  #pragma unroll
  for (int vf = 0; vf < 4; ++vf)
    #pragma unroll
    for (int r = 0; r < 4; ++r) {
      int row = q0 + g*4 + r;
      int col = h*64 + vf*16 + fr;
      Ctx[((size_t)b * 2048 + row) * 1024 + col] = f2bf(oacc[vf][r] / lrw[r]);
    }
}

extern "C" void kernel_launch(void* const* d_in, const int* in_sizes, int n_in,
                              void* d_out, int out_size, void* d_ws, size_t ws_size,
                              hipStream_t stream)
{
  const float* Qin = (const float*)d_in[0];
  const float* Wq  = (const float*)d_in[1];
  const float* Wk  = (const float*)d_in[2];
  const float* Wv  = (const float*)d_in[3];
  const float* Wo  = (const float*)d_in[4];
  float* out = (float*)d_out;

  u16* Xb  = (u16*)d_ws;                 // 4096*1024   Q_input bf16
  u16* WT  = Xb  + (size_t)4096*1024;    // 1152*1024   [Wq^T; Wk^T; Wv^T]
  u16* WoT = WT  + (size_t)1152*1024;    // 1024*1024   Wo^T
  u16* Qb  = WoT + (size_t)1024*1024;    // 4096*1024   Q proj
  u16* Kb  = Qb  + (size_t)4096*1024;    // 4096*64     K proj
  u16* Vtb = Kb  + (size_t)4096*64;      // 2*64*2048   V^T proj (k-permuted)
  u16* Ctx = Vtb + (size_t)2*64*2048;    // 4096*1024   attention out

  mqa_cvt<<<2048, 256, 0, stream>>>(Qin, Xb, 4096*1024/8);
  mqa_tcvt<<<dim3(32,32), 256, 0, stream>>>(Wq, WT, 1024, 1024);
  mqa_tcvt<<<dim3(2,32),  256, 0, stream>>>(Wk, WT + (size_t)1024*1024, 1024, 64);
  mqa_tcvt<<<dim3(2,32),  256, 0, stream>>>(Wv, WT + (size_t)1088*1024, 1024, 64);
  mqa_tcvt<<<dim3(32,32), 256, 0, stream>>>(Wo, WoT, 1024, 1024);

  mqa_gemm<1><<<32*9, 256, 0, stream>>>(Xb, WT, nullptr, Qb, Kb, Vtb,
                                        4096, 1152, 1024, 9);
  mqa_attn<<<dim3(32,16,2), 256, 0, stream>>>(Qb, Kb, Vtb, Ctx);
  mqa_gemm<0><<<32*8, 256, 0, stream>>>(Ctx, WoT, out, nullptr, nullptr, nullptr,
                                        4096, 1024, 1024, 8);
}

// Round 3
// 206.407 us; speedup vs baseline: 1.4601x; 1.4601x over previous
//
#include <hip/hip_runtime.h>

typedef __attribute__((ext_vector_type(8))) short bf16x8;
typedef __attribute__((ext_vector_type(4))) float f32x4;
typedef __attribute__((ext_vector_type(4))) unsigned int u32x4;
typedef unsigned short u16;

#define MFMA16(a,b,c) __builtin_amdgcn_mfma_f32_16x16x32_bf16((a),(b),(c),0,0,0)

__device__ __forceinline__ u16 f2bf(float f){
  unsigned int u = __float_as_uint(f);
  u += 0x7fffu + ((u >> 16) & 1u);
  return (u16)(u >> 16);
}

__device__ __forceinline__ unsigned int cvtpk(float lo, float hi){
  unsigned int r;
  asm("v_cvt_pk_bf16_f32 %0, %1, %2" : "=v"(r) : "v"(lo), "v"(hi));
  return r;
}

__device__ __forceinline__ void gload16(const void* g, void* l){
  __builtin_amdgcn_global_load_lds(
      (__attribute__((address_space(1))) void*)g,
      (__attribute__((address_space(3))) void*)l, 16, 0, 0);
}

// ---------------- prepass: fp32 -> bf16 flat convert ----------------
__global__ __launch_bounds__(256) void mqa_cvt(const float* __restrict__ in,
                                               u16* __restrict__ out, int n8){
  int i = blockIdx.x * 256 + threadIdx.x;
  if (i >= n8) return;
  const float4* p = (const float4*)in;
  float4 a = p[2*i], b = p[2*i+1];
  u16 o[8] = { f2bf(a.x), f2bf(a.y), f2bf(a.z), f2bf(a.w),
               f2bf(b.x), f2bf(b.y), f2bf(b.z), f2bf(b.w) };
  *(bf16x8*)&out[(size_t)i*8] = *(bf16x8*)o;
}

// ---------------- prepass: transpose-convert  in[R][C] f32 -> out[C][R] bf16
__global__ __launch_bounds__(256) void mqa_tcvt(const float* __restrict__ in,
                                                u16* __restrict__ out, int R, int C){
  __shared__ float t[32][33];
  int c0 = blockIdx.x * 32, r0 = blockIdx.y * 32;
  int x = threadIdx.x & 31, y0 = threadIdx.x >> 5;
  #pragma unroll
  for (int yy = y0; yy < 32; yy += 8)
    t[yy][x] = in[(size_t)(r0 + yy) * C + c0 + x];
  __syncthreads();
  #pragma unroll
  for (int yy = y0; yy < 32; yy += 8)
    out[(size_t)(c0 + yy) * R + r0 + x] = f2bf(t[x][yy]);
}

// ---------------- GEMM: A[M][K] bf16 row-major, Bt[N][K] bf16 row-major ----
// C = A * Bt^T.  EPI 0: fp32 out.  EPI 1: QKV scatter.
// V stored k-PERMUTED within each 64-key block: pos bits [k5 k3 k2 k4 k1 k0]
// -- matches the attention PV A-fragment slot order so PV needs no shuffles.
template<int EPI>
__global__ __launch_bounds__(256, 2) void mqa_gemm(
    const u16* __restrict__ A, const u16* __restrict__ Bt,
    float* __restrict__ outF, u16* __restrict__ Qb, u16* __restrict__ Kb,
    u16* __restrict__ Vtb, int M, int N, int K, int NT)
{
  __shared__ __align__(16) u16 lds_a[128*32];
  __shared__ __align__(16) u16 lds_b[128*32];
  int bx = blockIdx.x;
  int mt = bx / NT, nt = bx % NT;
  int m0 = mt * 128, n0 = nt * 128;
  int tid = threadIdx.x;
  int wid = tid >> 6, lane = tid & 63;
  int wrow = (wid >> 1) * 64, wcol = (wid & 1) * 64;
  int lrow = lane >> 2;
  int lk   = (lane & 3) * 8;
  int fr = lane & 15, g8 = (lane >> 4) * 8, fg = lane >> 4;

  f32x4 acc[4][4];
  #pragma unroll
  for (int i = 0; i < 4; ++i)
    #pragma unroll
    for (int j = 0; j < 4; ++j) acc[i][j] = (f32x4)0.f;

  for (int k0 = 0; k0 < K; k0 += 32) {
    #pragma unroll
    for (int c = wid; c < 8; c += 4) {
      gload16(&A [(size_t)(m0 + c*16 + lrow) * K + k0 + lk], &lds_a[c*512]);
      gload16(&Bt[(size_t)(n0 + c*16 + lrow) * K + k0 + lk], &lds_b[c*512]);
    }
    __syncthreads();
    bf16x8 af[4], bfr[4];
    #pragma unroll
    for (int i = 0; i < 4; ++i) af[i] = *(const bf16x8*)&lds_a[(wrow + i*16 + fr)*32 + g8];
    #pragma unroll
    for (int j = 0; j < 4; ++j) bfr[j] = *(const bf16x8*)&lds_b[(wcol + j*16 + fr)*32 + g8];
    #pragma unroll
    for (int i = 0; i < 4; ++i)
      #pragma unroll
      for (int j = 0; j < 4; ++j)
        acc[i][j] = MFMA16(af[i], bfr[j], acc[i][j]);
    __syncthreads();
  }

  #pragma unroll
  for (int i = 0; i < 4; ++i) {
    #pragma unroll
    for (int j = 0; j < 4; ++j) {
      int ncol = n0 + wcol + j*16 + fr;
      #pragma unroll
      for (int r = 0; r < 4; ++r) {
        int m = m0 + wrow + i*16 + fg*4 + r;
        float v = acc[i][j][r];
        if (EPI == 0) {
          outF[(size_t)m * N + ncol] = v;
        } else {
          u16 bv = f2bf(v);
          if (ncol < 1024) {
            Qb[(size_t)m * 1024 + ncol] = bv;              // Q [B,S,H*HD]
          } else if (ncol < 1088) {
            Kb[(size_t)m * 64 + (ncol - 1024)] = bv;       // K [B,S,HD]
          } else {
            int b = m >> 11, s = m & 2047;                 // Vp [B,HD,S-perm]
            int k = s & 63;
            int pos = (k & 35) | ((k & 12) << 1) | ((k & 16) >> 2);
            Vtb[((size_t)b * 64 + (ncol - 1088)) * 2048 + (s & ~63) + pos] = bv;
          }
        }
      }
    }
  }
}

// ---------------- flash MQA attention, swapped-QK^T, zero-LDS ----------------
// grid (S/128, H, B), 256 threads = 4 waves; wave w owns q rows [qt*128+w*32,+32)
__global__ __launch_bounds__(256, 4) void mqa_attn(
    const u16* __restrict__ Qb, const u16* __restrict__ Kb,
    const u16* __restrict__ Vtb, u16* __restrict__ Ctx)
{
  const float C1 = 0.18033688011112042f;  // (1/8) * log2(e)
  int qt = blockIdx.x, h = blockIdx.y, b = blockIdx.z;
  int tid = threadIdx.x, wid = tid >> 6, lane = tid & 63;
  int fr = lane & 15, g = lane >> 4;
  int q0 = qt * 128 + wid * 32;

  const u16* Qbase = Qb + (size_t)b * 2048 * 1024 + (size_t)h * 64;
  const u16* Kbase = Kb + (size_t)b * 2048 * 64;
  const u16* Vbase = Vtb + (size_t)b * 64 * 2048;

  // Q as the MFMA B-operand: lane(fr,g) slot j = Q[q = qf*16+fr][d = ks*32+g*8+j]
  bf16x8 qfv[2][2];
  #pragma unroll
  for (int qf_ = 0; qf_ < 2; ++qf_)
    #pragma unroll
    for (int ks = 0; ks < 2; ++ks)
      qfv[qf_][ks] = *(const bf16x8*)&Qbase[(size_t)(q0 + qf_*16 + fr) * 1024 + ks*32 + g*8];

  f32x4 oacc[2][4];
  #pragma unroll
  for (int qf_ = 0; qf_ < 2; ++qf_)
    #pragma unroll
    for (int vf = 0; vf < 4; ++vf) oacc[qf_][vf] = (f32x4)0.f;
  float m0v = -1e30f, m1v = -1e30f, l0 = 0.f, l1 = 0.f;

  for (int kb = 0; kb < 32; ++kb) {
    const int sk0 = kb * 64;
    f32x4 sacc[2][4];
    #pragma unroll
    for (int qf_ = 0; qf_ < 2; ++qf_)
      #pragma unroll
      for (int kf = 0; kf < 4; ++kf) sacc[qf_][kf] = (f32x4)0.f;

    // S^T = K Q^T : lane(fr,g) gets S[k = kf*16+g*4+r][q = qf*16+fr]
    __builtin_amdgcn_s_setprio(1);
    #pragma unroll
    for (int ks = 0; ks < 2; ++ks) {
      #pragma unroll
      for (int kf = 0; kf < 4; ++kf) {
        bf16x8 kfr = *(const bf16x8*)&Kbase[(size_t)(sk0 + kf*16 + fr) * 64 + ks*32 + g*8];
        sacc[0][kf] = MFMA16(kfr, qfv[0][ks], sacc[0][kf]);
        sacc[1][kf] = MFMA16(kfr, qfv[1][ks], sacc[1][kf]);
      }
    }
    __builtin_amdgcn_s_setprio(0);

    // per-q (lane-local) max over 16 scores, then reduce across the 4 g-lanes
    float pm0 = sacc[0][0][0], pm1 = sacc[1][0][0];
    #pragma unroll
    for (int kf = 0; kf < 4; ++kf)
      #pragma unroll
      for (int r = 0; r < 4; ++r) {
        pm0 = fmaxf(pm0, sacc[0][kf][r]);
        pm1 = fmaxf(pm1, sacc[1][kf][r]);
      }
    pm0 = fmaxf(pm0, __shfl_xor(pm0, 16)); pm0 = fmaxf(pm0, __shfl_xor(pm0, 32));
    pm1 = fmaxf(pm1, __shfl_xor(pm1, 16)); pm1 = fmaxf(pm1, __shfl_xor(pm1, 32));

    // T13 defer-max: skip rescale unless some row's max grew past +32 (raw)
    int defer = (pm0 <= m0v + 32.f) && (pm1 <= m1v + 32.f);
    if (!__all(defer)) {
      float n0 = fmaxf(m0v, pm0), n1 = fmaxf(m1v, pm1);
      float c0 = __builtin_amdgcn_exp2f((m0v - n0) * C1);
      float c1 = __builtin_amdgcn_exp2f((m1v - n1) * C1);
      m0v = n0; m1v = n1; l0 *= c0; l1 *= c1;
      #pragma unroll
      for (int vf = 0; vf < 4; ++vf) {
        #pragma unroll
        for (int r = 0; r < 4; ++r) { oacc[0][vf][r] *= c0; oacc[1][vf][r] *= c1; }
      }
    }

    // exp -> packed bf16 PV A-fragment slots, fully in-register
    float mc0 = m0v * C1, mc1 = m1v * C1;
    unsigned int pk0[8], pk1[8];
    float s0 = 0.f, s1 = 0.f;
    #pragma unroll
    for (int kf = 0; kf < 4; ++kf) {
      float a0 = __builtin_amdgcn_exp2f(sacc[0][kf][0] * C1 - mc0);
      float a1 = __builtin_amdgcn_exp2f(sacc[0][kf][1] * C1 - mc0);
      float a2 = __builtin_amdgcn_exp2f(sacc[0][kf][2] * C1 - mc0);
      float a3 = __builtin_amdgcn_exp2f(sacc[0][kf][3] * C1 - mc0);
      s0 += (a0 + a1) + (a2 + a3);
      pk0[2*kf]   = cvtpk(a0, a1);
      pk0[2*kf+1] = cvtpk(a2, a3);
      float b0 = __builtin_amdgcn_exp2f(sacc[1][kf][0] * C1 - mc1);
      float b1 = __builtin_amdgcn_exp2f(sacc[1][kf][1] * C1 - mc1);
      float b2 = __builtin_amdgcn_exp2f(sacc[1][kf][2] * C1 - mc1);
      float b3 = __builtin_amdgcn_exp2f(sacc[1][kf][3] * C1 - mc1);
      s1 += (b0 + b1) + (b2 + b3);
      pk1[2*kf]   = cvtpk(b0, b1);
      pk1[2*kf+1] = cvtpk(b2, b3);
    }
    s0 += __shfl_xor(s0, 16); s0 += __shfl_xor(s0, 32); l0 += s0;
    s1 += __shfl_xor(s1, 16); s1 += __shfl_xor(s1, 32); l1 += s1;

    // ctx += P V : A = packed P (slot k-order matches V's stored permutation)
    __builtin_amdgcn_s_setprio(1);
    #pragma unroll
    for (int ks2 = 0; ks2 < 2; ++ks2) {
      u32x4 w0 = { pk0[4*ks2], pk0[4*ks2+1], pk0[4*ks2+2], pk0[4*ks2+3] };
      u32x4 w1 = { pk1[4*ks2], pk1[4*ks2+1], pk1[4*ks2+2], pk1[4*ks2+3] };
      bf16x8 pA0 = __builtin_bit_cast(bf16x8, w0);
      bf16x8 pA1 = __builtin_bit_cast(bf16x8, w1);
      #pragma unroll
      for (int vf = 0; vf < 4; ++vf) {
        bf16x8 vfr = *(const bf16x8*)&Vbase[(size_t)(vf*16 + fr) * 2048 + sk0 + ks2*32 + g*8];
        oacc[0][vf] = MFMA16(pA0, vfr, oacc[0][vf]);
        oacc[1][vf] = MFMA16(pA1, vfr, oacc[1][vf]);
      }
    }
    __builtin_amdgcn_s_setprio(0);
  }

  // final: lane(fr,g) holds ctx[q = qf*16+g*4+r][d = vf*16+fr]; fetch that row's l
  #pragma unroll
  for (int qf_ = 0; qf_ < 2; ++qf_) {
    float lsrc = qf_ ? l1 : l0;
    #pragma unroll
    for (int r = 0; r < 4; ++r) {
      float lw = __shfl(lsrc, g*4 + r);
      float rl = 1.f / lw;
      int row = q0 + qf_*16 + g*4 + r;
      #pragma unroll
      for (int vf = 0; vf < 4; ++vf) {
        int col = h*64 + vf*16 + fr;
        Ctx[((size_t)b * 2048 + row) * 1024 + col] = f2bf(oacc[qf_][vf][r] * rl);
      }
    }
  }
}

extern "C" void kernel_launch(void* const* d_in, const int* in_sizes, int n_in,
                              void* d_out, int out_size, void* d_ws, size_t ws_size,
                              hipStream_t stream)
{
  const float* Qin = (const float*)d_in[0];
  const float* Wq  = (const float*)d_in[1];
  const float* Wk  = (const float*)d_in[2];
  const float* Wv  = (const float*)d_in[3];
  const float* Wo  = (const float*)d_in[4];
  float* out = (float*)d_out;

  u16* Xb  = (u16*)d_ws;                 // 4096*1024   Q_input bf16
  u16* WT  = Xb  + (size_t)4096*1024;    // 1152*1024   [Wq^T; Wk^T; Wv^T]
  u16* WoT = WT  + (size_t)1152*1024;    // 1024*1024   Wo^T
  u16* Qb  = WoT + (size_t)1024*1024;    // 4096*1024   Q proj
  u16* Kb  = Qb  + (size_t)4096*1024;    // 4096*64     K proj
  u16* Vtb = Kb  + (size_t)4096*64;      // 2*64*2048   V^T proj (k-permuted)
  u16* Ctx = Vtb + (size_t)2*64*2048;    // 4096*1024   attention out

  mqa_cvt<<<2048, 256, 0, stream>>>(Qin, Xb, 4096*1024/8);
  mqa_tcvt<<<dim3(32,32), 256, 0, stream>>>(Wq, WT, 1024, 1024);
  mqa_tcvt<<<dim3(2,32),  256, 0, stream>>>(Wk, WT + (size_t)1024*1024, 1024, 64);
  mqa_tcvt<<<dim3(2,32),  256, 0, stream>>>(Wv, WT + (size_t)1088*1024, 1024, 64);
  mqa_tcvt<<<dim3(32,32), 256, 0, stream>>>(Wo, WoT, 1024, 1024);

  mqa_gemm<1><<<32*9, 256, 0, stream>>>(Xb, WT, nullptr, Qb, Kb, Vtb,
                                        4096, 1152, 1024, 9);
  mqa_attn<<<dim3(16,16,2), 256, 0, stream>>>(Qb, Kb, Vtb, Ctx);
  mqa_gemm<0><<<32*8, 256, 0, stream>>>(Ctx, WoT, out, nullptr, nullptr, nullptr,
                                        4096, 1024, 1024, 8);
}